// Round 2
// baseline (626.192 us; speedup 1.0000x reference)
//
#include <hip/hip_runtime.h>
#include <hip/hip_bf16.h>

// NATLayer fp32 I/O, bf16 internal. B=8, H=W=128, C=128, HEADS=4, d=32, K=7,
// N=16384 (1-D neighborhood over flattened N), M = B*N = 131072.
//
// Round 7: occupancy fix. LDS 80.1KB -> 52.5KB so 3 blocks/CU fit
// (prev build measured OccupancyPercent ~23.5% == exactly 1 block/CU).
//  - halo 8 -> 3 rows (K=7 needs +/-3): xs/kv rows 80 -> 70. QKV GEMM still
//    M=80 tiles; rows >=70 read allocated-garbage LDS, discarded in epilogue.
//  - xres dropped: proj residual re-reads x from global; x2 residual carried
//    in 16 VGPRs from P4 to the final store (identical C-frag layout).
//  - kv stride 264 -> 256 with row&7 XOR key; qo/ct/ys stride-128 swz8.
// LDS shorts (26880 = 53760 B):
//   region A [0,8960):      xs[70][128] swz8; overlays qo[64][128], ys[64][128]
//   region B [8960,26880):  kv[70][256] swzK; overlays ct[64][128], h[64][256]
#define NPOS 16384
#define MROWS 131072

typedef unsigned short ushort_t;
typedef __bf16 bf8 __attribute__((ext_vector_type(8)));
typedef float f4 __attribute__((ext_vector_type(4)));

#define P_QKV_W 0
#define P_QKV_B 49152
#define P_PROJ_W 49536
#define P_PROJ_B 65920
#define P_FC1_W 66048
#define P_FC1_B 131584
#define P_FC2_W 132096
#define P_FC2_B 197632
#define P_TOTAL 197760

__device__ __forceinline__ float b2f(ushort_t u) {
    union { unsigned int i; float f; } v; v.i = ((unsigned int)u) << 16; return v.f;
}
__device__ __forceinline__ ushort_t f2b(float f) {
    __hip_bfloat16 h = __float2bfloat16(f);
    return *reinterpret_cast<ushort_t*>(&h);
}
// stride-128 tile: key row&7 (128 shorts == 0 mod 32 banks)
__device__ __forceinline__ int swz8(int row, int col) {
    return row * 128 + ((((col >> 3) ^ (row & 7)) << 3) | (col & 7));
}
// stride-256 tile: 512B stride is also bank-aligned -> same key strength
__device__ __forceinline__ int swzK(int row, int col) {
    return row * 256 + ((((col >> 3) ^ (row & 7)) << 3) | (col & 7));
}
__device__ __forceinline__ void ld8(const ushort_t* p, float* d) {
    uint4 pv = *(const uint4*)p;
    const ushort_t* us = (const ushort_t*)&pv;
    #pragma unroll
    for (int e = 0; e < 8; e++) d[e] = b2f(us[e]);
}
__device__ __forceinline__ void st8(ushort_t* p, const float* d) {
    unsigned int pk[4];
    #pragma unroll
    for (int e = 0; e < 4; e++)
        pk[e] = (unsigned int)f2b(d[2 * e]) | ((unsigned int)f2b(d[2 * e + 1]) << 16);
    *(uint4*)p = *(uint4*)pk;
}
__device__ __forceinline__ float fast_gelu(float x) {
    float u = x * (0.7978845608f + 0.0356774081f * x * x);
    float t = 1.0f - 2.0f / (1.0f + __expf(2.0f * u));
    return 0.5f * x * (1.0f + t);
}

__global__ __launch_bounds__(256) void cvt_params(
    const float* __restrict__ qkv_w, const float* __restrict__ qkv_b,
    const float* __restrict__ proj_w, const float* __restrict__ proj_b,
    const float* __restrict__ fc1_w, const float* __restrict__ fc1_b,
    const float* __restrict__ fc2_w, const float* __restrict__ fc2_b,
    ushort_t* __restrict__ p)
{
    int i = blockIdx.x * 256 + threadIdx.x;
    if (i >= P_TOTAL) return;
    float v;
    if      (i < P_QKV_B)  v = qkv_w[i - P_QKV_W];
    else if (i < P_PROJ_W) v = qkv_b[i - P_QKV_B];
    else if (i < P_PROJ_B) v = proj_w[i - P_PROJ_W];
    else if (i < P_FC1_W)  v = proj_b[i - P_PROJ_B];
    else if (i < P_FC1_B)  v = fc1_w[i - P_FC1_W];
    else if (i < P_FC2_W)  v = fc1_b[i - P_FC1_B];
    else if (i < P_FC2_B)  v = fc2_w[i - P_FC2_W];
    else                   v = fc2_b[i - P_FC2_B];
    p[i] = f2b(v);
}

// row mapping: LDS row i (0..69) <-> global token (nl0 - 3 + i), clamped.
// Q tokens nl0..nl0+63 are GEMM rows 3..66.
__global__ __launch_bounds__(512, 6) void k_fused(
    const float* __restrict__ x, const float* __restrict__ n1w,
    const float* __restrict__ n1b, const ushort_t* __restrict__ qkvw,
    const float* __restrict__ qkvb, const float* __restrict__ rpb,
    const ushort_t* __restrict__ projw, const float* __restrict__ projb,
    const float* __restrict__ n2w, const float* __restrict__ n2b,
    const ushort_t* __restrict__ fc1w, const float* __restrict__ fc1b,
    const ushort_t* __restrict__ fc2w, const float* __restrict__ fc2b,
    float* __restrict__ out)
{
    extern __shared__ ushort_t sm[];
    ushort_t* xs = sm;           // [70][128] swz8
    ushort_t* kv = sm + 8960;    // [70][256] swzK
    ushort_t* qo = sm;           // overlay: [64][128] swz8 (Q then attn-out)
    ushort_t* ct = sm + 8960;    // overlay: [64][128] swz8 (x2 for LN2)
    ushort_t* ys = sm;           // overlay: [64][128] swz8 (LN2 out)
    ushort_t* h  = sm + 8960;    // overlay: [64][256] swzK (gelu(fc1))

    int t0  = blockIdx.x * 64;
    int ib  = t0 & ~(NPOS - 1);
    int nl0 = t0 & (NPOS - 1);
    int tid = threadIdx.x;
    int w = tid >> 6, lane = tid & 63;
    int quad = lane >> 4, lrow = lane & 15;

    // ---- phase 1: LN1 of 70 rows (16 lanes/row, 8 ch/lane)
    {
        int grp = tid >> 4, l = tid & 15;
        int c0 = l * 8;
        float4 wa = *(const float4*)&n1w[c0], wb = *(const float4*)&n1w[c0 + 4];
        float4 ba = *(const float4*)&n1b[c0], bb = *(const float4*)&n1b[c0 + 4];
        float w8[8] = {wa.x, wa.y, wa.z, wa.w, wb.x, wb.y, wb.z, wb.w};
        float b8[8] = {ba.x, ba.y, ba.z, ba.w, bb.x, bb.y, bb.z, bb.w};
        #pragma unroll
        for (int pass = 0; pass < 3; pass++) {
            int r = pass * 32 + grp;
            if (r < 70) {
                int nl = min(max(nl0 - 3 + r, 0), NPOS - 1);
                const float* xp = &x[(size_t)(ib + nl) * 128 + c0];
                float4 va = *(const float4*)xp;
                float4 vb = *(const float4*)(xp + 4);
                float v[8] = {va.x, va.y, va.z, va.w, vb.x, vb.y, vb.z, vb.w};
                float s = 0.f, s2 = 0.f;
                #pragma unroll
                for (int e = 0; e < 8; e++) { s += v[e]; s2 += v[e] * v[e]; }
                #pragma unroll
                for (int off = 8; off; off >>= 1) {
                    s  += __shfl_xor(s,  off, 64);
                    s2 += __shfl_xor(s2, off, 64);
                }
                float mu   = s * (1.0f / 128.0f);
                float rstd = rsqrtf(s2 * (1.0f / 128.0f) - mu * mu + 1e-5f);
                float o[8];
                #pragma unroll
                for (int e = 0; e < 8; e++) o[e] = (v[e] - mu) * rstd * w8[e] + b8[e];
                st8(&xs[swz8(r, c0)], o);
            }
        }
    }
    __syncthreads();

    // ---- phase 2: QKV GEMM. M=80 tiles (rows >=70 garbage, discarded),
    //      N=384 (24 tiles, 3/wave)
    {
        f4 acc[5][3];
        #pragma unroll
        for (int i = 0; i < 5; i++)
            #pragma unroll
            for (int j = 0; j < 3; j++) { f4 z = {0.f,0.f,0.f,0.f}; acc[i][j] = z; }
        #pragma unroll
        for (int k0 = 0; k0 < 128; k0 += 32) {
            bf8 bv[3];
            #pragma unroll
            for (int jj = 0; jj < 3; jj++) {
                int n = (3 * w + jj) * 16 + lrow;
                bv[jj] = *(const bf8*)&qkvw[(size_t)n * 128 + k0 + quad * 8];
            }
            #pragma unroll
            for (int i = 0; i < 5; i++) {
                bf8 av = *(const bf8*)&xs[swz8(i * 16 + lrow, k0 + quad * 8)];
                #pragma unroll
                for (int jj = 0; jj < 3; jj++)
                    acc[i][jj] = __builtin_amdgcn_mfma_f32_16x16x32_bf16(
                        av, bv[jj], acc[i][jj], 0, 0, 0);
            }
        }
        __syncthreads();          // xs reads done before qo overlay writes
        #pragma unroll
        for (int jj = 0; jj < 3; jj++) {
            int jt = 3 * w + jj;
            int n = jt * 16 + lrow;
            float bj = qkvb[n];
            #pragma unroll
            for (int i = 0; i < 5; i++) {
                #pragma unroll
                for (int r = 0; r < 4; r++) {
                    int g = i * 16 + quad * 4 + r;
                    float v = acc[i][jj][r] + bj;
                    if (jt < 8) {
                        if (g >= 3 && g < 67)
                            qo[swz8(g - 3, n)] = f2b(v * 0.17677669529663687f);
                    } else {
                        if (g < 70)
                            kv[swzK(g, n - 128)] = f2b(v);
                    }
                }
            }
        }
    }
    __syncthreads();

    // ---- phase 3: attention. thread = (token=tid>>3, head=(tid>>1)&3, half=tid&1)
    {
        int t = tid >> 3, head = (tid >> 1) & 3, half = tid & 1;
        int n = nl0 + t;
        int s = n - 3;
        if (s < 0) s = 0;
        if (s > NPOS - 7) s = NPOS - 7;
        int r0 = s - nl0 + 3;            // kv row of neighbor j=0 (3..63)
        int cb = head * 32 + half * 16;

        float q[16];
        ld8(&qo[swz8(t, cb)], q);
        ld8(&qo[swz8(t, cb + 8)], q + 8);

        float logit[7];
        #pragma unroll
        for (int j = 0; j < 7; j++) {
            int row = r0 + j;
            float kk[8];
            float p = 0.f;
            ld8(&kv[swzK(row, cb)], kk);
            #pragma unroll
            for (int e = 0; e < 8; e++) p += q[e] * kk[e];
            ld8(&kv[swzK(row, cb + 8)], kk);
            #pragma unroll
            for (int e = 0; e < 8; e++) p += q[8 + e] * kk[e];
            p += __shfl_xor(p, 1, 64);   // combine the two 16-chan halves
            logit[j] = p + rpb[head * 13 + (s + j - n + 6)];
        }
        float m = logit[0];
        #pragma unroll
        for (int j = 1; j < 7; j++) m = fmaxf(m, logit[j]);
        float e[7], esum = 0.f;
        #pragma unroll
        for (int j = 0; j < 7; j++) { e[j] = __expf(logit[j] - m); esum += e[j]; }
        float inv = 1.0f / esum;

        float o[16];
        #pragma unroll
        for (int c = 0; c < 16; c++) o[c] = 0.f;
        #pragma unroll
        for (int j = 0; j < 7; j++) {
            int row = r0 + j;
            float vv[8];
            float ej = e[j];
            ld8(&kv[swzK(row, 128 + cb)], vv);
            #pragma unroll
            for (int c = 0; c < 8; c++) o[c] += ej * vv[c];
            ld8(&kv[swzK(row, 128 + cb + 8)], vv);
            #pragma unroll
            for (int c = 0; c < 8; c++) o[8 + c] += ej * vv[c];
        }
        #pragma unroll
        for (int c = 0; c < 16; c++) o[c] *= inv;
        st8(&qo[swz8(t, cb)], o);
        st8(&qo[swz8(t, cb + 8)], o + 8);
    }
    __syncthreads();

    // ---- phase 4: proj (M=64, N=128; wave w owns N-tile w) + x resid
    //      x2 kept in 16 VGPRs (res) AND written bf16 to ct for LN2.
    float res[16];
    {
        int n = w * 16 + lrow;
        float xr[16];
        #pragma unroll
        for (int i = 0; i < 4; i++)
            #pragma unroll
            for (int r = 0; r < 4; r++)
                xr[i * 4 + r] = x[(size_t)(t0 + i * 16 + quad * 4 + r) * 128 + n];
        f4 acc2[4];
        #pragma unroll
        for (int i = 0; i < 4; i++) { f4 z = {0.f,0.f,0.f,0.f}; acc2[i] = z; }
        #pragma unroll
        for (int k0 = 0; k0 < 128; k0 += 32) {
            bf8 bv = *(const bf8*)&projw[(size_t)n * 128 + k0 + quad * 8];
            #pragma unroll
            for (int i = 0; i < 4; i++) {
                bf8 av = *(const bf8*)&qo[swz8(i * 16 + lrow, k0 + quad * 8)];
                acc2[i] = __builtin_amdgcn_mfma_f32_16x16x32_bf16(av, bv, acc2[i], 0, 0, 0);
            }
        }
        float bj = projb[n];
        __syncthreads();   // qo reads (all waves) done before ct writes? ct!=qo region; but kv reads in P3 done before ct overlay writes
        #pragma unroll
        for (int i = 0; i < 4; i++) {
            #pragma unroll
            for (int r = 0; r < 4; r++) {
                int row = i * 16 + quad * 4 + r;
                float v = acc2[i][r] + bj + xr[i * 4 + r];
                res[i * 4 + r] = v;
                ct[swz8(row, n)] = f2b(v);
            }
        }
    }
    __syncthreads();

    // ---- phase 5: LN2 (16 lanes/row) ct -> ys (overlays qo; qo dead)
    {
        int grp = tid >> 4, l = tid & 15;
        int c0 = l * 8;
        float4 wa = *(const float4*)&n2w[c0], wb = *(const float4*)&n2w[c0 + 4];
        float4 ba = *(const float4*)&n2b[c0], bb = *(const float4*)&n2b[c0 + 4];
        float w8[8] = {wa.x, wa.y, wa.z, wa.w, wb.x, wb.y, wb.z, wb.w};
        float b8[8] = {ba.x, ba.y, ba.z, ba.w, bb.x, bb.y, bb.z, bb.w};
        #pragma unroll
        for (int pass = 0; pass < 2; pass++) {
            int t = pass * 32 + grp;
            float v[8];
            ld8(&ct[swz8(t, c0)], v);
            float s = 0.f, s2 = 0.f;
            #pragma unroll
            for (int e = 0; e < 8; e++) { s += v[e]; s2 += v[e] * v[e]; }
            #pragma unroll
            for (int off = 8; off; off >>= 1) {
                s  += __shfl_xor(s,  off, 64);
                s2 += __shfl_xor(s2, off, 64);
            }
            float mu   = s * (1.0f / 128.0f);
            float rstd = rsqrtf(s2 * (1.0f / 128.0f) - mu * mu + 1e-5f);
            float o[8];
            #pragma unroll
            for (int e = 0; e < 8; e++) o[e] = (v[e] - mu) * rstd * w8[e] + b8[e];
            st8(&ys[swz8(t, c0)], o);
        }
    }
    __syncthreads();

    // ---- phase 6: fc1 + gelu + fc2 (256-wide K-halves) + x2 resid from regs
    {
        f4 acc2[4];
        #pragma unroll
        for (int i = 0; i < 4; i++) { f4 z = {0.f,0.f,0.f,0.f}; acc2[i] = z; }
        int n = w * 16 + lrow;

        for (int hh = 0; hh < 2; hh++) {
            // fc1: local N=256 (16 tiles, 2/wave), K=128
            f4 acc[4][2];
            #pragma unroll
            for (int i = 0; i < 4; i++)
                #pragma unroll
                for (int j = 0; j < 2; j++) { f4 z = {0.f,0.f,0.f,0.f}; acc[i][j] = z; }
            #pragma unroll
            for (int k0 = 0; k0 < 128; k0 += 32) {
                bf8 bv[2];
                #pragma unroll
                for (int jj = 0; jj < 2; jj++) {
                    int frow = hh * 256 + (w * 2 + jj) * 16 + lrow;
                    bv[jj] = *(const bf8*)&fc1w[(size_t)frow * 128 + k0 + quad * 8];
                }
                #pragma unroll
                for (int i = 0; i < 4; i++) {
                    bf8 av = *(const bf8*)&ys[swz8(i * 16 + lrow, k0 + quad * 8)];
                    #pragma unroll
                    for (int jj = 0; jj < 2; jj++)
                        acc[i][jj] = __builtin_amdgcn_mfma_f32_16x16x32_bf16(
                            av, bv[jj], acc[i][jj], 0, 0, 0);
                }
            }
            __syncthreads();   // ct (hh=0) / prior fc2 h-reads (hh=1) done
            #pragma unroll
            for (int jj = 0; jj < 2; jj++) {
                int cb = (w * 2 + jj) * 16 + lrow;        // local col 0..255
                float bj = fc1b[hh * 256 + cb];
                #pragma unroll
                for (int i = 0; i < 4; i++) {
                    #pragma unroll
                    for (int r = 0; r < 4; r++) {
                        int row = i * 16 + quad * 4 + r;
                        h[swzK(row, cb)] = f2b(fast_gelu(acc[i][jj][r] + bj));
                    }
                }
            }
            __syncthreads();
            // fc2 partial: K-half 256
            #pragma unroll
            for (int k0 = 0; k0 < 256; k0 += 32) {
                bf8 bv = *(const bf8*)&fc2w[(size_t)n * 512 + hh * 256 + k0 + quad * 8];
                #pragma unroll
                for (int i = 0; i < 4; i++) {
                    bf8 av = *(const bf8*)&h[swzK(i * 16 + lrow, k0 + quad * 8)];
                    acc2[i] = __builtin_amdgcn_mfma_f32_16x16x32_bf16(av, bv, acc2[i], 0, 0, 0);
                }
            }
        }

        float bj = fc2b[n];
        #pragma unroll
        for (int i = 0; i < 4; i++) {
            #pragma unroll
            for (int r = 0; r < 4; r++) {
                int grow = t0 + i * 16 + quad * 4 + r;
                out[(size_t)grow * 128 + n] = acc2[i][r] + bj + res[i * 4 + r];
            }
        }
    }
}

extern "C" void kernel_launch(void* const* d_in, const int* in_sizes, int n_in,
                              void* d_out, int out_size, void* d_ws, size_t ws_size,
                              hipStream_t stream) {
    const float* x      = (const float*)d_in[0];
    const float* n1w    = (const float*)d_in[1];
    const float* n1b    = (const float*)d_in[2];
    const float* qkv_w  = (const float*)d_in[3];
    const float* qkv_b  = (const float*)d_in[4];
    const float* rpb    = (const float*)d_in[5];
    const float* proj_w = (const float*)d_in[6];
    const float* proj_b = (const float*)d_in[7];
    const float* n2w    = (const float*)d_in[8];
    const float* n2b    = (const float*)d_in[9];
    const float* fc1_w  = (const float*)d_in[10];
    const float* fc1_b  = (const float*)d_in[11];
    const float* fc2_w  = (const float*)d_in[12];
    const float* fc2_b  = (const float*)d_in[13];

    ushort_t* params = (ushort_t*)d_ws;
    float*    outf   = (float*)d_out;

    cvt_params<<<(P_TOTAL + 255) / 256, 256, 0, stream>>>(
        qkv_w, qkv_b, proj_w, proj_b, fc1_w, fc1_b, fc2_w, fc2_b, params);

    k_fused<<<MROWS / 64, 512, 53760, stream>>>(
        x, n1w, n1b, params + P_QKV_W, qkv_b, rpb,
        params + P_PROJ_W, proj_b, n2w, n2b,
        params + P_FC1_W, fc1_b, params + P_FC2_W, fc2_b, outf);
}

// Round 3
// 303.716 us; speedup vs baseline: 2.0618x; 2.0618x over previous
//
#include <hip/hip_runtime.h>
#include <hip/hip_bf16.h>

// NATLayer fp32 I/O, bf16 internal. B=8, H=W=128, C=128, HEADS=4, d=32, K=7,
// N=16384 (1-D neighborhood over flattened N), M = B*N = 131072.
//
// Round 8: spill fix. Round 7 forced __launch_bounds__(512,6) + 32 extra live
// floats -> allocator squeezed 68->40 VGPR, ~1.6 GB scratch traffic, 560us.
//  - __launch_bounds__(512,4): cap 128, natural ~68 VGPR, no spill; occupancy
//    becomes LDS-limited at 3 blocks/CU (3 x 53760 B = 161280 <= 163840).
//  - res[16] dropped: final residual reads bf16 x2 from ct (LDS). MLP now
//    runs 128-wide K-QUARTERS so h[64][128] fits beside ct[64][128] in
//    region B (was 256-wide halves with h[64][256] destroying ct).
//  - xr[16] dropped: x residual loaded inline in P4 epilogue.
// LDS shorts (26880 = 53760 B):
//   region A [0,8960):      xs[70][128] swz8; overlays qo[64][128], ys[64][128]
//   region B [8960,26880):  kv[70][256] swzK; overlays ct[64][128] @8960,
//                           h[64][128] @17152
#define NPOS 16384
#define MROWS 131072

typedef unsigned short ushort_t;
typedef __bf16 bf8 __attribute__((ext_vector_type(8)));
typedef float f4 __attribute__((ext_vector_type(4)));

#define P_QKV_W 0
#define P_QKV_B 49152
#define P_PROJ_W 49536
#define P_PROJ_B 65920
#define P_FC1_W 66048
#define P_FC1_B 131584
#define P_FC2_W 132096
#define P_FC2_B 197632
#define P_TOTAL 197760

__device__ __forceinline__ float b2f(ushort_t u) {
    union { unsigned int i; float f; } v; v.i = ((unsigned int)u) << 16; return v.f;
}
__device__ __forceinline__ ushort_t f2b(float f) {
    __hip_bfloat16 h = __float2bfloat16(f);
    return *reinterpret_cast<ushort_t*>(&h);
}
// stride-128 tile: key row&7 (128 shorts == 0 mod 32 banks)
__device__ __forceinline__ int swz8(int row, int col) {
    return row * 128 + ((((col >> 3) ^ (row & 7)) << 3) | (col & 7));
}
// stride-256 tile: 512B stride is also bank-aligned -> same key strength
__device__ __forceinline__ int swzK(int row, int col) {
    return row * 256 + ((((col >> 3) ^ (row & 7)) << 3) | (col & 7));
}
__device__ __forceinline__ void ld8(const ushort_t* p, float* d) {
    uint4 pv = *(const uint4*)p;
    const ushort_t* us = (const ushort_t*)&pv;
    #pragma unroll
    for (int e = 0; e < 8; e++) d[e] = b2f(us[e]);
}
__device__ __forceinline__ void st8(ushort_t* p, const float* d) {
    unsigned int pk[4];
    #pragma unroll
    for (int e = 0; e < 4; e++)
        pk[e] = (unsigned int)f2b(d[2 * e]) | ((unsigned int)f2b(d[2 * e + 1]) << 16);
    *(uint4*)p = *(uint4*)pk;
}
__device__ __forceinline__ float fast_gelu(float x) {
    float u = x * (0.7978845608f + 0.0356774081f * x * x);
    float t = 1.0f - 2.0f / (1.0f + __expf(2.0f * u));
    return 0.5f * x * (1.0f + t);
}

__global__ __launch_bounds__(256) void cvt_params(
    const float* __restrict__ qkv_w, const float* __restrict__ qkv_b,
    const float* __restrict__ proj_w, const float* __restrict__ proj_b,
    const float* __restrict__ fc1_w, const float* __restrict__ fc1_b,
    const float* __restrict__ fc2_w, const float* __restrict__ fc2_b,
    ushort_t* __restrict__ p)
{
    int i = blockIdx.x * 256 + threadIdx.x;
    if (i >= P_TOTAL) return;
    float v;
    if      (i < P_QKV_B)  v = qkv_w[i - P_QKV_W];
    else if (i < P_PROJ_W) v = qkv_b[i - P_QKV_B];
    else if (i < P_PROJ_B) v = proj_w[i - P_PROJ_W];
    else if (i < P_FC1_W)  v = proj_b[i - P_PROJ_B];
    else if (i < P_FC1_B)  v = fc1_w[i - P_FC1_W];
    else if (i < P_FC2_W)  v = fc1_b[i - P_FC1_B];
    else if (i < P_FC2_B)  v = fc2_w[i - P_FC2_W];
    else                   v = fc2_b[i - P_FC2_B];
    p[i] = f2b(v);
}

// row mapping: LDS row i (0..69) <-> global token (nl0 - 3 + i), clamped.
// Q tokens nl0..nl0+63 are GEMM rows 3..66.
__global__ __launch_bounds__(512, 4) void k_fused(
    const float* __restrict__ x, const float* __restrict__ n1w,
    const float* __restrict__ n1b, const ushort_t* __restrict__ qkvw,
    const float* __restrict__ qkvb, const float* __restrict__ rpb,
    const ushort_t* __restrict__ projw, const float* __restrict__ projb,
    const float* __restrict__ n2w, const float* __restrict__ n2b,
    const ushort_t* __restrict__ fc1w, const float* __restrict__ fc1b,
    const ushort_t* __restrict__ fc2w, const float* __restrict__ fc2b,
    float* __restrict__ out)
{
    extern __shared__ ushort_t sm[];
    ushort_t* xs = sm;           // [70][128] swz8
    ushort_t* kv = sm + 8960;    // [70][256] swzK
    ushort_t* qo = sm;           // overlay: [64][128] swz8 (Q then attn-out)
    ushort_t* ct = sm + 8960;    // overlay: [64][128] swz8 (x2, lives to end)
    ushort_t* ys = sm;           // overlay: [64][128] swz8 (LN2 out)
    ushort_t* h  = sm + 17152;   // overlay: [64][128] swz8 (gelu(fc1) quarter)

    int t0  = blockIdx.x * 64;
    int ib  = t0 & ~(NPOS - 1);
    int nl0 = t0 & (NPOS - 1);
    int tid = threadIdx.x;
    int w = tid >> 6, lane = tid & 63;
    int quad = lane >> 4, lrow = lane & 15;

    // ---- phase 1: LN1 of 70 rows (16 lanes/row, 8 ch/lane)
    {
        int grp = tid >> 4, l = tid & 15;
        int c0 = l * 8;
        float4 wa = *(const float4*)&n1w[c0], wb = *(const float4*)&n1w[c0 + 4];
        float4 ba = *(const float4*)&n1b[c0], bb = *(const float4*)&n1b[c0 + 4];
        float w8[8] = {wa.x, wa.y, wa.z, wa.w, wb.x, wb.y, wb.z, wb.w};
        float b8[8] = {ba.x, ba.y, ba.z, ba.w, bb.x, bb.y, bb.z, bb.w};
        #pragma unroll
        for (int pass = 0; pass < 3; pass++) {
            int r = pass * 32 + grp;
            if (r < 70) {
                int nl = min(max(nl0 - 3 + r, 0), NPOS - 1);
                const float* xp = &x[(size_t)(ib + nl) * 128 + c0];
                float4 va = *(const float4*)xp;
                float4 vb = *(const float4*)(xp + 4);
                float v[8] = {va.x, va.y, va.z, va.w, vb.x, vb.y, vb.z, vb.w};
                float s = 0.f, s2 = 0.f;
                #pragma unroll
                for (int e = 0; e < 8; e++) { s += v[e]; s2 += v[e] * v[e]; }
                #pragma unroll
                for (int off = 8; off; off >>= 1) {
                    s  += __shfl_xor(s,  off, 64);
                    s2 += __shfl_xor(s2, off, 64);
                }
                float mu   = s * (1.0f / 128.0f);
                float rstd = rsqrtf(s2 * (1.0f / 128.0f) - mu * mu + 1e-5f);
                float o[8];
                #pragma unroll
                for (int e = 0; e < 8; e++) o[e] = (v[e] - mu) * rstd * w8[e] + b8[e];
                st8(&xs[swz8(r, c0)], o);
            }
        }
    }
    __syncthreads();

    // ---- phase 2: QKV GEMM. M=80 tiles (rows >=70 garbage, discarded),
    //      N=384 (24 tiles, 3/wave)
    {
        f4 acc[5][3];
        #pragma unroll
        for (int i = 0; i < 5; i++)
            #pragma unroll
            for (int j = 0; j < 3; j++) { f4 z = {0.f,0.f,0.f,0.f}; acc[i][j] = z; }
        #pragma unroll
        for (int k0 = 0; k0 < 128; k0 += 32) {
            bf8 bv[3];
            #pragma unroll
            for (int jj = 0; jj < 3; jj++) {
                int n = (3 * w + jj) * 16 + lrow;
                bv[jj] = *(const bf8*)&qkvw[(size_t)n * 128 + k0 + quad * 8];
            }
            #pragma unroll
            for (int i = 0; i < 5; i++) {
                bf8 av = *(const bf8*)&xs[swz8(i * 16 + lrow, k0 + quad * 8)];
                #pragma unroll
                for (int jj = 0; jj < 3; jj++)
                    acc[i][jj] = __builtin_amdgcn_mfma_f32_16x16x32_bf16(
                        av, bv[jj], acc[i][jj], 0, 0, 0);
            }
        }
        __syncthreads();          // xs reads done before qo overlay writes
        #pragma unroll
        for (int jj = 0; jj < 3; jj++) {
            int jt = 3 * w + jj;
            int n = jt * 16 + lrow;
            float bj = qkvb[n];
            #pragma unroll
            for (int i = 0; i < 5; i++) {
                #pragma unroll
                for (int r = 0; r < 4; r++) {
                    int g = i * 16 + quad * 4 + r;
                    float v = acc[i][jj][r] + bj;
                    if (jt < 8) {
                        if (g >= 3 && g < 67)
                            qo[swz8(g - 3, n)] = f2b(v * 0.17677669529663687f);
                    } else {
                        if (g < 70)
                            kv[swzK(g, n - 128)] = f2b(v);
                    }
                }
            }
        }
    }
    __syncthreads();

    // ---- phase 3: attention. thread = (token=tid>>3, head=(tid>>1)&3, half=tid&1)
    {
        int t = tid >> 3, head = (tid >> 1) & 3, half = tid & 1;
        int n = nl0 + t;
        int s = n - 3;
        if (s < 0) s = 0;
        if (s > NPOS - 7) s = NPOS - 7;
        int r0 = s - nl0 + 3;            // kv row of neighbor j=0
        int cb = head * 32 + half * 16;

        float q[16];
        ld8(&qo[swz8(t, cb)], q);
        ld8(&qo[swz8(t, cb + 8)], q + 8);

        float logit[7];
        #pragma unroll
        for (int j = 0; j < 7; j++) {
            int row = r0 + j;
            float kk[8];
            float p = 0.f;
            ld8(&kv[swzK(row, cb)], kk);
            #pragma unroll
            for (int e = 0; e < 8; e++) p += q[e] * kk[e];
            ld8(&kv[swzK(row, cb + 8)], kk);
            #pragma unroll
            for (int e = 0; e < 8; e++) p += q[8 + e] * kk[e];
            p += __shfl_xor(p, 1, 64);   // combine the two 16-chan halves
            logit[j] = p + rpb[head * 13 + (s + j - n + 6)];
        }
        float m = logit[0];
        #pragma unroll
        for (int j = 1; j < 7; j++) m = fmaxf(m, logit[j]);
        float e[7], esum = 0.f;
        #pragma unroll
        for (int j = 0; j < 7; j++) { e[j] = __expf(logit[j] - m); esum += e[j]; }
        float inv = 1.0f / esum;

        float o[16];
        #pragma unroll
        for (int c = 0; c < 16; c++) o[c] = 0.f;
        #pragma unroll
        for (int j = 0; j < 7; j++) {
            int row = r0 + j;
            float vv[8];
            float ej = e[j];
            ld8(&kv[swzK(row, 128 + cb)], vv);
            #pragma unroll
            for (int c = 0; c < 8; c++) o[c] += ej * vv[c];
            ld8(&kv[swzK(row, 128 + cb + 8)], vv);
            #pragma unroll
            for (int c = 0; c < 8; c++) o[8 + c] += ej * vv[c];
        }
        #pragma unroll
        for (int c = 0; c < 16; c++) o[c] *= inv;
        st8(&qo[swz8(t, cb)], o);
        st8(&qo[swz8(t, cb + 8)], o + 8);
    }
    __syncthreads();

    // ---- phase 4: proj (M=64, N=128; wave w owns N-tile w) + x resid -> ct
    {
        int n = w * 16 + lrow;
        f4 acc2[4];
        #pragma unroll
        for (int i = 0; i < 4; i++) { f4 z = {0.f,0.f,0.f,0.f}; acc2[i] = z; }
        #pragma unroll
        for (int k0 = 0; k0 < 128; k0 += 32) {
            bf8 bv = *(const bf8*)&projw[(size_t)n * 128 + k0 + quad * 8];
            #pragma unroll
            for (int i = 0; i < 4; i++) {
                bf8 av = *(const bf8*)&qo[swz8(i * 16 + lrow, k0 + quad * 8)];
                acc2[i] = __builtin_amdgcn_mfma_f32_16x16x32_bf16(av, bv, acc2[i], 0, 0, 0);
            }
        }
        float bj = projb[n];
        #pragma unroll
        for (int i = 0; i < 4; i++) {
            #pragma unroll
            for (int r = 0; r < 4; r++) {
                int row = i * 16 + quad * 4 + r;
                float xv = x[(size_t)(t0 + row) * 128 + n];
                ct[swz8(row, n)] = f2b(acc2[i][r] + bj + xv);
            }
        }
    }
    __syncthreads();

    // ---- phase 5: LN2 (16 lanes/row) ct -> ys (overlays qo; qo dead)
    {
        int grp = tid >> 4, l = tid & 15;
        int c0 = l * 8;
        float4 wa = *(const float4*)&n2w[c0], wb = *(const float4*)&n2w[c0 + 4];
        float4 ba = *(const float4*)&n2b[c0], bb = *(const float4*)&n2b[c0 + 4];
        float w8[8] = {wa.x, wa.y, wa.z, wa.w, wb.x, wb.y, wb.z, wb.w};
        float b8[8] = {ba.x, ba.y, ba.z, ba.w, bb.x, bb.y, bb.z, bb.w};
        #pragma unroll
        for (int pass = 0; pass < 2; pass++) {
            int t = pass * 32 + grp;
            float v[8];
            ld8(&ct[swz8(t, c0)], v);
            float s = 0.f, s2 = 0.f;
            #pragma unroll
            for (int e = 0; e < 8; e++) { s += v[e]; s2 += v[e] * v[e]; }
            #pragma unroll
            for (int off = 8; off; off >>= 1) {
                s  += __shfl_xor(s,  off, 64);
                s2 += __shfl_xor(s2, off, 64);
            }
            float mu   = s * (1.0f / 128.0f);
            float rstd = rsqrtf(s2 * (1.0f / 128.0f) - mu * mu + 1e-5f);
            float o[8];
            #pragma unroll
            for (int e = 0; e < 8; e++) o[e] = (v[e] - mu) * rstd * w8[e] + b8[e];
            st8(&ys[swz8(t, c0)], o);
        }
    }
    __syncthreads();

    // ---- phase 6: fc1 + gelu + fc2 by 128-wide K-QUARTERS (h[64][128]
    //      coexists with ct) + x2 resid from ct at the end.
    {
        f4 acc2[4];
        #pragma unroll
        for (int i = 0; i < 4; i++) { f4 z = {0.f,0.f,0.f,0.f}; acc2[i] = z; }
        int n = w * 16 + lrow;

        for (int qq = 0; qq < 4; qq++) {
            // fc1 quarter: local N=128 (8 tiles, 1/wave), K=128
            f4 acc[4];
            #pragma unroll
            for (int i = 0; i < 4; i++) { f4 z = {0.f,0.f,0.f,0.f}; acc[i] = z; }
            int frow = qq * 128 + w * 16 + lrow;
            #pragma unroll
            for (int k0 = 0; k0 < 128; k0 += 32) {
                bf8 bv = *(const bf8*)&fc1w[(size_t)frow * 128 + k0 + quad * 8];
                #pragma unroll
                for (int i = 0; i < 4; i++) {
                    bf8 av = *(const bf8*)&ys[swz8(i * 16 + lrow, k0 + quad * 8)];
                    acc[i] = __builtin_amdgcn_mfma_f32_16x16x32_bf16(
                        av, bv, acc[i], 0, 0, 0);
                }
            }
            __syncthreads();   // prior quarter's fc2 done reading h
            {
                int cb = w * 16 + lrow;               // local col 0..127
                float bj = fc1b[qq * 128 + cb];
                #pragma unroll
                for (int i = 0; i < 4; i++) {
                    #pragma unroll
                    for (int r = 0; r < 4; r++) {
                        int row = i * 16 + quad * 4 + r;
                        h[swz8(row, cb)] = f2b(fast_gelu(acc[i][r] + bj));
                    }
                }
            }
            __syncthreads();
            // fc2 partial: K-quarter 128
            #pragma unroll
            for (int k0 = 0; k0 < 128; k0 += 32) {
                bf8 bv = *(const bf8*)&fc2w[(size_t)n * 512 + qq * 128 + k0 + quad * 8];
                #pragma unroll
                for (int i = 0; i < 4; i++) {
                    bf8 av = *(const bf8*)&h[swz8(i * 16 + lrow, k0 + quad * 8)];
                    acc2[i] = __builtin_amdgcn_mfma_f32_16x16x32_bf16(av, bv, acc2[i], 0, 0, 0);
                }
            }
        }

        float bj = fc2b[n];
        #pragma unroll
        for (int i = 0; i < 4; i++) {
            #pragma unroll
            for (int r = 0; r < 4; r++) {
                int row = i * 16 + quad * 4 + r;
                out[(size_t)(t0 + row) * 128 + n] =
                    acc2[i][r] + bj + b2f(ct[swz8(row, n)]);
            }
        }
    }
}

extern "C" void kernel_launch(void* const* d_in, const int* in_sizes, int n_in,
                              void* d_out, int out_size, void* d_ws, size_t ws_size,
                              hipStream_t stream) {
    const float* x      = (const float*)d_in[0];
    const float* n1w    = (const float*)d_in[1];
    const float* n1b    = (const float*)d_in[2];
    const float* qkv_w  = (const float*)d_in[3];
    const float* qkv_b  = (const float*)d_in[4];
    const float* rpb    = (const float*)d_in[5];
    const float* proj_w = (const float*)d_in[6];
    const float* proj_b = (const float*)d_in[7];
    const float* n2w    = (const float*)d_in[8];
    const float* n2b    = (const float*)d_in[9];
    const float* fc1_w  = (const float*)d_in[10];
    const float* fc1_b  = (const float*)d_in[11];
    const float* fc2_w  = (const float*)d_in[12];
    const float* fc2_b  = (const float*)d_in[13];

    ushort_t* params = (ushort_t*)d_ws;
    float*    outf   = (float*)d_out;

    cvt_params<<<(P_TOTAL + 255) / 256, 256, 0, stream>>>(
        qkv_w, qkv_b, proj_w, proj_b, fc1_w, fc1_b, fc2_w, fc2_b, params);

    k_fused<<<MROWS / 64, 512, 53760, stream>>>(
        x, n1w, n1b, params + P_QKV_W, qkv_b, rpb,
        params + P_PROJ_W, proj_b, n2w, n2b,
        params + P_FC1_W, fc1_b, params + P_FC2_W, fc2_b, outf);
}

// Round 4
// 277.797 us; speedup vs baseline: 2.2541x; 1.0933x over previous
//
#include <hip/hip_runtime.h>
#include <hip/hip_bf16.h>

// NATLayer fp32 I/O, bf16 internal. B=8, H=W=128, C=128, HEADS=4, d=32, K=7,
// N=16384 (1-D neighborhood over flattened N), M = B*N = 131072.
//
// Round 9: transposed-C epilogues. All GEMM MFMAs issue mfma(bv, av) so the
// C-fragment is transposed: lane holds 4 CONSECUTIVE N-columns of one M-row.
// Epilogues become packed ds_write_b64 / float4 / dwordx4 ops instead of
// scalar b16 writes (was ~150 scalar DS + ~40 scalar global ops per thread,
// the source of 11M bank conflicts and ~50% VALUBusy at MfmaUtil 11%).
//  - P2 QKV epilogue: 60 b16 writes -> 15 b64; bias float4; branch hoisted.
//  - P4 proj: 16 -> 4 b64 writes; x residual 16 scalar -> 4 float4 loads.
//  - P6 fc1: 64 -> 16 b64 writes; out 16 scalar -> 4 dwordx4 stores;
//    ct residual 16 scalar -> 4 b64 reads.
// LDS shorts (26880 = 53760 B):
//   region A [0,8960):      xs[70][128] swz8; overlays qo[64][128], ys[64][128]
//   region B [8960,26880):  kv[70][256] swzK; overlays ct[64][128] @8960,
//                           h[64][128] @17152
#define NPOS 16384
#define MROWS 131072

typedef unsigned short ushort_t;
typedef __bf16 bf8 __attribute__((ext_vector_type(8)));
typedef float f4 __attribute__((ext_vector_type(4)));

#define P_QKV_W 0
#define P_QKV_B 49152
#define P_PROJ_W 49536
#define P_PROJ_B 65920
#define P_FC1_W 66048
#define P_FC1_B 131584
#define P_FC2_W 132096
#define P_FC2_B 197632
#define P_TOTAL 197760

__device__ __forceinline__ float b2f(ushort_t u) {
    union { unsigned int i; float f; } v; v.i = ((unsigned int)u) << 16; return v.f;
}
__device__ __forceinline__ ushort_t f2b(float f) {
    __hip_bfloat16 h = __float2bfloat16(f);
    return *reinterpret_cast<ushort_t*>(&h);
}
// stride-128 tile: key row&7 (128 shorts == 0 mod 32 banks)
__device__ __forceinline__ int swz8(int row, int col) {
    return row * 128 + ((((col >> 3) ^ (row & 7)) << 3) | (col & 7));
}
// stride-256 tile: 512B stride is also bank-aligned -> same key strength
__device__ __forceinline__ int swzK(int row, int col) {
    return row * 256 + ((((col >> 3) ^ (row & 7)) << 3) | (col & 7));
}
__device__ __forceinline__ void ld8(const ushort_t* p, float* d) {
    uint4 pv = *(const uint4*)p;
    const ushort_t* us = (const ushort_t*)&pv;
    #pragma unroll
    for (int e = 0; e < 8; e++) d[e] = b2f(us[e]);
}
__device__ __forceinline__ void st8(ushort_t* p, const float* d) {
    unsigned int pk[4];
    #pragma unroll
    for (int e = 0; e < 4; e++)
        pk[e] = (unsigned int)f2b(d[2 * e]) | ((unsigned int)f2b(d[2 * e + 1]) << 16);
    *(uint4*)p = *(uint4*)pk;
}
// 4 floats -> 4 bf16 packed, one b64 LDS write (4-short-aligned target)
__device__ __forceinline__ void st4(ushort_t* p, const float* d) {
    unsigned int pk[2];
    pk[0] = (unsigned int)f2b(d[0]) | ((unsigned int)f2b(d[1]) << 16);
    pk[1] = (unsigned int)f2b(d[2]) | ((unsigned int)f2b(d[3]) << 16);
    *(uint2*)p = *(uint2*)pk;
}
__device__ __forceinline__ void ld4(const ushort_t* p, float* d) {
    uint2 pv = *(const uint2*)p;
    const ushort_t* us = (const ushort_t*)&pv;
    #pragma unroll
    for (int e = 0; e < 4; e++) d[e] = b2f(us[e]);
}
__device__ __forceinline__ float fast_gelu(float x) {
    float u = x * (0.7978845608f + 0.0356774081f * x * x);
    float t = 1.0f - 2.0f / (1.0f + __expf(2.0f * u));
    return 0.5f * x * (1.0f + t);
}

__global__ __launch_bounds__(256) void cvt_params(
    const float* __restrict__ qkv_w, const float* __restrict__ qkv_b,
    const float* __restrict__ proj_w, const float* __restrict__ proj_b,
    const float* __restrict__ fc1_w, const float* __restrict__ fc1_b,
    const float* __restrict__ fc2_w, const float* __restrict__ fc2_b,
    ushort_t* __restrict__ p)
{
    int i = blockIdx.x * 256 + threadIdx.x;
    if (i >= P_TOTAL) return;
    float v;
    if      (i < P_QKV_B)  v = qkv_w[i - P_QKV_W];
    else if (i < P_PROJ_W) v = qkv_b[i - P_QKV_B];
    else if (i < P_PROJ_B) v = proj_w[i - P_PROJ_W];
    else if (i < P_FC1_W)  v = proj_b[i - P_PROJ_B];
    else if (i < P_FC1_B)  v = fc1_w[i - P_FC1_W];
    else if (i < P_FC2_W)  v = fc1_b[i - P_FC1_B];
    else if (i < P_FC2_B)  v = fc2_w[i - P_FC2_W];
    else                   v = fc2_b[i - P_FC2_B];
    p[i] = f2b(v);
}

// row mapping: LDS row i (0..69) <-> global token (nl0 - 3 + i), clamped.
// Q tokens nl0..nl0+63 are GEMM rows 3..66.
__global__ __launch_bounds__(512, 4) void k_fused(
    const float* __restrict__ x, const float* __restrict__ n1w,
    const float* __restrict__ n1b, const ushort_t* __restrict__ qkvw,
    const float* __restrict__ qkvb, const float* __restrict__ rpb,
    const ushort_t* __restrict__ projw, const float* __restrict__ projb,
    const float* __restrict__ n2w, const float* __restrict__ n2b,
    const ushort_t* __restrict__ fc1w, const float* __restrict__ fc1b,
    const ushort_t* __restrict__ fc2w, const float* __restrict__ fc2b,
    float* __restrict__ out)
{
    extern __shared__ ushort_t sm[];
    ushort_t* xs = sm;           // [70][128] swz8
    ushort_t* kv = sm + 8960;    // [70][256] swzK
    ushort_t* qo = sm;           // overlay: [64][128] swz8 (Q then attn-out)
    ushort_t* ct = sm + 8960;    // overlay: [64][128] swz8 (x2, lives to end)
    ushort_t* ys = sm;           // overlay: [64][128] swz8 (LN2 out)
    ushort_t* h  = sm + 17152;   // overlay: [64][128] swz8 (gelu(fc1) quarter)

    int t0  = blockIdx.x * 64;
    int ib  = t0 & ~(NPOS - 1);
    int nl0 = t0 & (NPOS - 1);
    int tid = threadIdx.x;
    int w = tid >> 6, lane = tid & 63;
    int quad = lane >> 4, lrow = lane & 15;

    // ---- phase 1: LN1 of 70 rows (16 lanes/row, 8 ch/lane)
    {
        int grp = tid >> 4, l = tid & 15;
        int c0 = l * 8;
        float4 wa = *(const float4*)&n1w[c0], wb = *(const float4*)&n1w[c0 + 4];
        float4 ba = *(const float4*)&n1b[c0], bb = *(const float4*)&n1b[c0 + 4];
        float w8[8] = {wa.x, wa.y, wa.z, wa.w, wb.x, wb.y, wb.z, wb.w};
        float b8[8] = {ba.x, ba.y, ba.z, ba.w, bb.x, bb.y, bb.z, bb.w};
        #pragma unroll
        for (int pass = 0; pass < 3; pass++) {
            int r = pass * 32 + grp;
            if (r < 70) {
                int nl = min(max(nl0 - 3 + r, 0), NPOS - 1);
                const float* xp = &x[(size_t)(ib + nl) * 128 + c0];
                float4 va = *(const float4*)xp;
                float4 vb = *(const float4*)(xp + 4);
                float v[8] = {va.x, va.y, va.z, va.w, vb.x, vb.y, vb.z, vb.w};
                float s = 0.f, s2 = 0.f;
                #pragma unroll
                for (int e = 0; e < 8; e++) { s += v[e]; s2 += v[e] * v[e]; }
                #pragma unroll
                for (int off = 8; off; off >>= 1) {
                    s  += __shfl_xor(s,  off, 64);
                    s2 += __shfl_xor(s2, off, 64);
                }
                float mu   = s * (1.0f / 128.0f);
                float rstd = rsqrtf(s2 * (1.0f / 128.0f) - mu * mu + 1e-5f);
                float o[8];
                #pragma unroll
                for (int e = 0; e < 8; e++) o[e] = (v[e] - mu) * rstd * w8[e] + b8[e];
                st8(&xs[swz8(r, c0)], o);
            }
        }
    }
    __syncthreads();

    // ---- phase 2: QKV GEMM (transposed C). M=80 tiles, N=384 (3 tiles/wave)
    {
        f4 acc[5][3];
        #pragma unroll
        for (int i = 0; i < 5; i++)
            #pragma unroll
            for (int j = 0; j < 3; j++) { f4 z = {0.f,0.f,0.f,0.f}; acc[i][j] = z; }
        #pragma unroll
        for (int k0 = 0; k0 < 128; k0 += 32) {
            bf8 bv[3];
            #pragma unroll
            for (int jj = 0; jj < 3; jj++) {
                int n = (3 * w + jj) * 16 + lrow;
                bv[jj] = *(const bf8*)&qkvw[(size_t)n * 128 + k0 + quad * 8];
            }
            #pragma unroll
            for (int i = 0; i < 5; i++) {
                bf8 av = *(const bf8*)&xs[swz8(i * 16 + lrow, k0 + quad * 8)];
                #pragma unroll
                for (int jj = 0; jj < 3; jj++)
                    acc[i][jj] = __builtin_amdgcn_mfma_f32_16x16x32_bf16(
                        bv[jj], av, acc[i][jj], 0, 0, 0);   // C^T fragment
            }
        }
        __syncthreads();          // xs reads done before qo overlay writes
        #pragma unroll
        for (int jj = 0; jj < 3; jj++) {
            int jt = 3 * w + jj;
            int n0 = jt * 16 + quad * 4;         // 4 consecutive N-cols
            float4 b4 = *(const float4*)&qkvb[n0];
            #pragma unroll
            for (int i = 0; i < 5; i++) {
                int m = i * 16 + lrow;           // one M-row per lane
                float v[4];
                v[0] = acc[i][jj][0] + b4.x; v[1] = acc[i][jj][1] + b4.y;
                v[2] = acc[i][jj][2] + b4.z; v[3] = acc[i][jj][3] + b4.w;
                if (jt < 8) {
                    if (m >= 3 && m < 67) {
                        #pragma unroll
                        for (int r = 0; r < 4; r++) v[r] *= 0.17677669529663687f;
                        st4(&qo[swz8(m - 3, n0)], v);
                    }
                } else {
                    if (m < 70) st4(&kv[swzK(m, n0 - 128)], v);
                }
            }
        }
    }
    __syncthreads();

    // ---- phase 3: attention. thread = (token=tid>>3, head=(tid>>1)&3, half=tid&1)
    {
        int t = tid >> 3, head = (tid >> 1) & 3, half = tid & 1;
        int n = nl0 + t;
        int s = n - 3;
        if (s < 0) s = 0;
        if (s > NPOS - 7) s = NPOS - 7;
        int r0 = s - nl0 + 3;            // kv row of neighbor j=0
        int cb = head * 32 + half * 16;

        float q[16];
        ld8(&qo[swz8(t, cb)], q);
        ld8(&qo[swz8(t, cb + 8)], q + 8);

        float logit[7];
        #pragma unroll
        for (int j = 0; j < 7; j++) {
            int row = r0 + j;
            float kk[8];
            float p = 0.f;
            ld8(&kv[swzK(row, cb)], kk);
            #pragma unroll
            for (int e = 0; e < 8; e++) p += q[e] * kk[e];
            ld8(&kv[swzK(row, cb + 8)], kk);
            #pragma unroll
            for (int e = 0; e < 8; e++) p += q[8 + e] * kk[e];
            p += __shfl_xor(p, 1, 64);   // combine the two 16-chan halves
            logit[j] = p + rpb[head * 13 + (s + j - n + 6)];
        }
        float m = logit[0];
        #pragma unroll
        for (int j = 1; j < 7; j++) m = fmaxf(m, logit[j]);
        float e[7], esum = 0.f;
        #pragma unroll
        for (int j = 0; j < 7; j++) { e[j] = __expf(logit[j] - m); esum += e[j]; }
        float inv = 1.0f / esum;

        float o[16];
        #pragma unroll
        for (int c = 0; c < 16; c++) o[c] = 0.f;
        #pragma unroll
        for (int j = 0; j < 7; j++) {
            int row = r0 + j;
            float vv[8];
            float ej = e[j];
            ld8(&kv[swzK(row, 128 + cb)], vv);
            #pragma unroll
            for (int c = 0; c < 8; c++) o[c] += ej * vv[c];
            ld8(&kv[swzK(row, 128 + cb + 8)], vv);
            #pragma unroll
            for (int c = 0; c < 8; c++) o[8 + c] += ej * vv[c];
        }
        #pragma unroll
        for (int c = 0; c < 16; c++) o[c] *= inv;
        st8(&qo[swz8(t, cb)], o);
        st8(&qo[swz8(t, cb + 8)], o + 8);
    }
    __syncthreads();

    // ---- phase 4: proj (transposed C) + x resid (float4) -> ct (b64)
    {
        int nb = w * 16 + lrow;              // weight row for B-frag loads
        int n0 = w * 16 + quad * 4;          // 4 consecutive out cols
        f4 acc2[4];
        #pragma unroll
        for (int i = 0; i < 4; i++) { f4 z = {0.f,0.f,0.f,0.f}; acc2[i] = z; }
        #pragma unroll
        for (int k0 = 0; k0 < 128; k0 += 32) {
            bf8 bv = *(const bf8*)&projw[(size_t)nb * 128 + k0 + quad * 8];
            #pragma unroll
            for (int i = 0; i < 4; i++) {
                bf8 av = *(const bf8*)&qo[swz8(i * 16 + lrow, k0 + quad * 8)];
                acc2[i] = __builtin_amdgcn_mfma_f32_16x16x32_bf16(bv, av, acc2[i], 0, 0, 0);
            }
        }
        float4 b4 = *(const float4*)&projb[n0];
        #pragma unroll
        for (int i = 0; i < 4; i++) {
            int m = i * 16 + lrow;
            float4 xv = *(const float4*)&x[(size_t)(t0 + m) * 128 + n0];
            float v[4];
            v[0] = acc2[i][0] + b4.x + xv.x; v[1] = acc2[i][1] + b4.y + xv.y;
            v[2] = acc2[i][2] + b4.z + xv.z; v[3] = acc2[i][3] + b4.w + xv.w;
            st4(&ct[swz8(m, n0)], v);
        }
    }
    __syncthreads();

    // ---- phase 5: LN2 (16 lanes/row) ct -> ys (overlays qo; qo dead)
    {
        int grp = tid >> 4, l = tid & 15;
        int c0 = l * 8;
        float4 wa = *(const float4*)&n2w[c0], wb = *(const float4*)&n2w[c0 + 4];
        float4 ba = *(const float4*)&n2b[c0], bb = *(const float4*)&n2b[c0 + 4];
        float w8[8] = {wa.x, wa.y, wa.z, wa.w, wb.x, wb.y, wb.z, wb.w};
        float b8[8] = {ba.x, ba.y, ba.z, ba.w, bb.x, bb.y, bb.z, bb.w};
        #pragma unroll
        for (int pass = 0; pass < 2; pass++) {
            int t = pass * 32 + grp;
            float v[8];
            ld8(&ct[swz8(t, c0)], v);
            float s = 0.f, s2 = 0.f;
            #pragma unroll
            for (int e = 0; e < 8; e++) { s += v[e]; s2 += v[e] * v[e]; }
            #pragma unroll
            for (int off = 8; off; off >>= 1) {
                s  += __shfl_xor(s,  off, 64);
                s2 += __shfl_xor(s2, off, 64);
            }
            float mu   = s * (1.0f / 128.0f);
            float rstd = rsqrtf(s2 * (1.0f / 128.0f) - mu * mu + 1e-5f);
            float o[8];
            #pragma unroll
            for (int e = 0; e < 8; e++) o[e] = (v[e] - mu) * rstd * w8[e] + b8[e];
            st8(&ys[swz8(t, c0)], o);
        }
    }
    __syncthreads();

    // ---- phase 6: fc1 + gelu + fc2 by 128-wide K-QUARTERS (transposed C
    //      throughout; h[64][128] coexists with ct) + x2 resid from ct.
    {
        f4 acc2[4];
        #pragma unroll
        for (int i = 0; i < 4; i++) { f4 z = {0.f,0.f,0.f,0.f}; acc2[i] = z; }
        int nb = w * 16 + lrow;              // fc2 weight row (loads)
        int n0 = w * 16 + quad * 4;          // out cols (epilogue)

        for (int qq = 0; qq < 4; qq++) {
            // fc1 quarter: local N=128 (8 tiles, 1/wave), K=128
            f4 acc[4];
            #pragma unroll
            for (int i = 0; i < 4; i++) { f4 z = {0.f,0.f,0.f,0.f}; acc[i] = z; }
            int frow = qq * 128 + w * 16 + lrow;   // fc1 weight row (loads)
            #pragma unroll
            for (int k0 = 0; k0 < 128; k0 += 32) {
                bf8 bv = *(const bf8*)&fc1w[(size_t)frow * 128 + k0 + quad * 8];
                #pragma unroll
                for (int i = 0; i < 4; i++) {
                    bf8 av = *(const bf8*)&ys[swz8(i * 16 + lrow, k0 + quad * 8)];
                    acc[i] = __builtin_amdgcn_mfma_f32_16x16x32_bf16(
                        bv, av, acc[i], 0, 0, 0);
                }
            }
            __syncthreads();   // prior quarter's fc2 done reading h
            {
                int hc0 = w * 16 + quad * 4;       // local hidden col base
                float4 b4 = *(const float4*)&fc1b[qq * 128 + hc0];
                float bb[4] = {b4.x, b4.y, b4.z, b4.w};
                #pragma unroll
                for (int i = 0; i < 4; i++) {
                    int m = i * 16 + lrow;
                    float v[4];
                    #pragma unroll
                    for (int r = 0; r < 4; r++)
                        v[r] = fast_gelu(acc[i][r] + bb[r]);
                    st4(&h[swz8(m, hc0)], v);
                }
            }
            __syncthreads();
            // fc2 partial: K-quarter 128
            #pragma unroll
            for (int k0 = 0; k0 < 128; k0 += 32) {
                bf8 bv = *(const bf8*)&fc2w[(size_t)nb * 512 + qq * 128 + k0 + quad * 8];
                #pragma unroll
                for (int i = 0; i < 4; i++) {
                    bf8 av = *(const bf8*)&h[swz8(i * 16 + lrow, k0 + quad * 8)];
                    acc2[i] = __builtin_amdgcn_mfma_f32_16x16x32_bf16(bv, av, acc2[i], 0, 0, 0);
                }
            }
        }

        float4 b4 = *(const float4*)&fc2b[n0];
        #pragma unroll
        for (int i = 0; i < 4; i++) {
            int m = i * 16 + lrow;
            float rv[4];
            ld4(&ct[swz8(m, n0)], rv);
            float4 o;
            o.x = acc2[i][0] + b4.x + rv[0];
            o.y = acc2[i][1] + b4.y + rv[1];
            o.z = acc2[i][2] + b4.z + rv[2];
            o.w = acc2[i][3] + b4.w + rv[3];
            *(float4*)&out[(size_t)(t0 + m) * 128 + n0] = o;
        }
    }
}

extern "C" void kernel_launch(void* const* d_in, const int* in_sizes, int n_in,
                              void* d_out, int out_size, void* d_ws, size_t ws_size,
                              hipStream_t stream) {
    const float* x      = (const float*)d_in[0];
    const float* n1w    = (const float*)d_in[1];
    const float* n1b    = (const float*)d_in[2];
    const float* qkv_w  = (const float*)d_in[3];
    const float* qkv_b  = (const float*)d_in[4];
    const float* rpb    = (const float*)d_in[5];
    const float* proj_w = (const float*)d_in[6];
    const float* proj_b = (const float*)d_in[7];
    const float* n2w    = (const float*)d_in[8];
    const float* n2b    = (const float*)d_in[9];
    const float* fc1_w  = (const float*)d_in[10];
    const float* fc1_b  = (const float*)d_in[11];
    const float* fc2_w  = (const float*)d_in[12];
    const float* fc2_b  = (const float*)d_in[13];

    ushort_t* params = (ushort_t*)d_ws;
    float*    outf   = (float*)d_out;

    cvt_params<<<(P_TOTAL + 255) / 256, 256, 0, stream>>>(
        qkv_w, qkv_b, proj_w, proj_b, fc1_w, fc1_b, fc2_w, fc2_b, params);

    k_fused<<<MROWS / 64, 512, 53760, stream>>>(
        x, n1w, n1b, params + P_QKV_W, qkv_b, rpb,
        params + P_PROJ_W, proj_b, n2w, n2b,
        params + P_FC1_W, fc1_b, params + P_FC2_W, fc2_b, outf);
}

// Round 6
// 275.207 us; speedup vs baseline: 2.2754x; 1.0094x over previous
//
#include <hip/hip_runtime.h>
#include <hip/hip_bf16.h>
#include <hip/hip_fp16.h>

// NATLayer fp32 I/O, bf16/f16 internal. B=8, H=W=128, C=128, HEADS=4, d=32,
// K=7, N=16384 (1-D neighborhood over flattened N), M = B*N = 131072.
//
// Round 11 == Round 10 resubmit (round-10 bench failed on container
// acquisition, not kernel error).
// Packed-f16 attention: Q/K/V/attn-out stored as _Float16 (same 2B/elem ->
// identical LDS layout), phase 3 uses __hfma2 (v_pk_fma_f16): no per-element
// bf16->f32 conversions (~240/thread gone) and half the FMA issue count.
// 1/esum folded into e[j]. proj GEMM switches to f16 MFMA (same fragment
// geometry); proj weights converted to f16 in cvt_params.
// LDS shorts (26880 = 53760 B):
//   region A [0,8960):      xs[70][128] swz8 (bf16); overlays qo[64][128]
//                           (f16), ys[64][128] (bf16)
//   region B [8960,26880):  kv[70][256] swzK (f16); overlays ct[64][128]
//                           (bf16) @8960, h[64][128] (bf16) @17152
#define NPOS 16384
#define MROWS 131072

typedef unsigned short ushort_t;
typedef __bf16 bf8 __attribute__((ext_vector_type(8)));
typedef _Float16 h8 __attribute__((ext_vector_type(8)));
typedef float f4 __attribute__((ext_vector_type(4)));

#define P_QKV_W 0
#define P_QKV_B 49152
#define P_PROJ_W 49536
#define P_PROJ_B 65920
#define P_FC1_W 66048
#define P_FC1_B 131584
#define P_FC2_W 132096
#define P_FC2_B 197632
#define P_TOTAL 197760

union H2U { __half2 h; unsigned int u; };

__device__ __forceinline__ float b2f(ushort_t u) {
    union { unsigned int i; float f; } v; v.i = ((unsigned int)u) << 16; return v.f;
}
__device__ __forceinline__ ushort_t f2b(float f) {
    __hip_bfloat16 h = __float2bfloat16(f);
    return *reinterpret_cast<ushort_t*>(&h);
}
// stride-128 tile: key row&7 (128 shorts == 0 mod 32 banks)
__device__ __forceinline__ int swz8(int row, int col) {
    return row * 128 + ((((col >> 3) ^ (row & 7)) << 3) | (col & 7));
}
// stride-256 tile: 512B stride is also bank-aligned -> same key strength
__device__ __forceinline__ int swzK(int row, int col) {
    return row * 256 + ((((col >> 3) ^ (row & 7)) << 3) | (col & 7));
}
__device__ __forceinline__ void ld8(const ushort_t* p, float* d) {
    uint4 pv = *(const uint4*)p;
    const ushort_t* us = (const ushort_t*)&pv;
    #pragma unroll
    for (int e = 0; e < 8; e++) d[e] = b2f(us[e]);
}
__device__ __forceinline__ void st8(ushort_t* p, const float* d) {
    unsigned int pk[4];
    #pragma unroll
    for (int e = 0; e < 4; e++)
        pk[e] = (unsigned int)f2b(d[2 * e]) | ((unsigned int)f2b(d[2 * e + 1]) << 16);
    *(uint4*)p = *(uint4*)pk;
}
// 4 floats -> 4 bf16 packed, one b64 LDS write
__device__ __forceinline__ void st4(ushort_t* p, const float* d) {
    unsigned int pk[2];
    pk[0] = (unsigned int)f2b(d[0]) | ((unsigned int)f2b(d[1]) << 16);
    pk[1] = (unsigned int)f2b(d[2]) | ((unsigned int)f2b(d[3]) << 16);
    *(uint2*)p = *(uint2*)pk;
}
// 4 floats -> 4 f16 packed, one b64 LDS write
__device__ __forceinline__ void st4h(ushort_t* p, const float* d) {
    H2U a, b;
    a.h = __floats2half2_rn(d[0], d[1]);
    b.h = __floats2half2_rn(d[2], d[3]);
    uint2 u; u.x = a.u; u.y = b.u;
    *(uint2*)p = u;
}
__device__ __forceinline__ void ld4(const ushort_t* p, float* d) {
    uint2 pv = *(const uint2*)p;
    const ushort_t* us = (const ushort_t*)&pv;
    #pragma unroll
    for (int e = 0; e < 4; e++) d[e] = b2f(us[e]);
}
// 8 f16 -> 4 half2 regs (no conversion)
__device__ __forceinline__ void ldh8(const ushort_t* p, __half2* d) {
    uint4 pv = *(const uint4*)p;
    H2U u;
    u.u = pv.x; d[0] = u.h;
    u.u = pv.y; d[1] = u.h;
    u.u = pv.z; d[2] = u.h;
    u.u = pv.w; d[3] = u.h;
}
__device__ __forceinline__ void sth8(ushort_t* p, const __half2* o) {
    H2U u0, u1, u2, u3;
    u0.h = o[0]; u1.h = o[1]; u2.h = o[2]; u3.h = o[3];
    uint4 pv; pv.x = u0.u; pv.y = u1.u; pv.z = u2.u; pv.w = u3.u;
    *(uint4*)p = pv;
}
__device__ __forceinline__ float fast_gelu(float x) {
    float u = x * (0.7978845608f + 0.0356774081f * x * x);
    float t = 1.0f - 2.0f / (1.0f + __expf(2.0f * u));
    return 0.5f * x * (1.0f + t);
}

__global__ __launch_bounds__(256) void cvt_params(
    const float* __restrict__ qkv_w, const float* __restrict__ qkv_b,
    const float* __restrict__ proj_w, const float* __restrict__ proj_b,
    const float* __restrict__ fc1_w, const float* __restrict__ fc1_b,
    const float* __restrict__ fc2_w, const float* __restrict__ fc2_b,
    ushort_t* __restrict__ p)
{
    int i = blockIdx.x * 256 + threadIdx.x;
    if (i >= P_TOTAL) return;
    float v;
    bool as_f16 = false;
    if      (i < P_QKV_B)  v = qkv_w[i - P_QKV_W];
    else if (i < P_PROJ_W) v = qkv_b[i - P_QKV_B];
    else if (i < P_PROJ_B) { v = proj_w[i - P_PROJ_W]; as_f16 = true; }
    else if (i < P_FC1_W)  v = proj_b[i - P_PROJ_B];
    else if (i < P_FC1_B)  v = fc1_w[i - P_FC1_W];
    else if (i < P_FC2_W)  v = fc1_b[i - P_FC1_B];
    else if (i < P_FC2_B)  v = fc2_w[i - P_FC2_W];
    else                   v = fc2_b[i - P_FC2_B];
    if (as_f16) {
        __half h = __float2half_rn(v);
        p[i] = *reinterpret_cast<ushort_t*>(&h);
    } else {
        p[i] = f2b(v);
    }
}

// row mapping: LDS row i (0..69) <-> global token (nl0 - 3 + i), clamped.
// Q tokens nl0..nl0+63 are GEMM rows 3..66.
__global__ __launch_bounds__(512, 4) void k_fused(
    const float* __restrict__ x, const float* __restrict__ n1w,
    const float* __restrict__ n1b, const ushort_t* __restrict__ qkvw,
    const float* __restrict__ qkvb, const float* __restrict__ rpb,
    const ushort_t* __restrict__ projw, const float* __restrict__ projb,
    const float* __restrict__ n2w, const float* __restrict__ n2b,
    const ushort_t* __restrict__ fc1w, const float* __restrict__ fc1b,
    const ushort_t* __restrict__ fc2w, const float* __restrict__ fc2b,
    float* __restrict__ out)
{
    extern __shared__ ushort_t sm[];
    ushort_t* xs = sm;           // [70][128] swz8 (bf16)
    ushort_t* kv = sm + 8960;    // [70][256] swzK (f16)
    ushort_t* qo = sm;           // overlay: [64][128] swz8 (f16 Q / attn-out)
    ushort_t* ct = sm + 8960;    // overlay: [64][128] swz8 (bf16 x2)
    ushort_t* ys = sm;           // overlay: [64][128] swz8 (bf16 LN2 out)
    ushort_t* h  = sm + 17152;   // overlay: [64][128] swz8 (bf16 gelu(fc1))

    int t0  = blockIdx.x * 64;
    int ib  = t0 & ~(NPOS - 1);
    int nl0 = t0 & (NPOS - 1);
    int tid = threadIdx.x;
    int w = tid >> 6, lane = tid & 63;
    int quad = lane >> 4, lrow = lane & 15;

    // ---- phase 1: LN1 of 70 rows (16 lanes/row, 8 ch/lane)
    {
        int grp = tid >> 4, l = tid & 15;
        int c0 = l * 8;
        float4 wa = *(const float4*)&n1w[c0], wb = *(const float4*)&n1w[c0 + 4];
        float4 ba = *(const float4*)&n1b[c0], bb = *(const float4*)&n1b[c0 + 4];
        float w8[8] = {wa.x, wa.y, wa.z, wa.w, wb.x, wb.y, wb.z, wb.w};
        float b8[8] = {ba.x, ba.y, ba.z, ba.w, bb.x, bb.y, bb.z, bb.w};
        #pragma unroll
        for (int pass = 0; pass < 3; pass++) {
            int r = pass * 32 + grp;
            if (r < 70) {
                int nl = min(max(nl0 - 3 + r, 0), NPOS - 1);
                const float* xp = &x[(size_t)(ib + nl) * 128 + c0];
                float4 va = *(const float4*)xp;
                float4 vb = *(const float4*)(xp + 4);
                float v[8] = {va.x, va.y, va.z, va.w, vb.x, vb.y, vb.z, vb.w};
                float s = 0.f, s2 = 0.f;
                #pragma unroll
                for (int e = 0; e < 8; e++) { s += v[e]; s2 += v[e] * v[e]; }
                #pragma unroll
                for (int off = 8; off; off >>= 1) {
                    s  += __shfl_xor(s,  off, 64);
                    s2 += __shfl_xor(s2, off, 64);
                }
                float mu   = s * (1.0f / 128.0f);
                float rstd = rsqrtf(s2 * (1.0f / 128.0f) - mu * mu + 1e-5f);
                float o[8];
                #pragma unroll
                for (int e = 0; e < 8; e++) o[e] = (v[e] - mu) * rstd * w8[e] + b8[e];
                st8(&xs[swz8(r, c0)], o);
            }
        }
    }
    __syncthreads();

    // ---- phase 2: QKV GEMM (transposed C). M=80 tiles, N=384 (3 tiles/wave)
    {
        f4 acc[5][3];
        #pragma unroll
        for (int i = 0; i < 5; i++)
            #pragma unroll
            for (int j = 0; j < 3; j++) { f4 z = {0.f,0.f,0.f,0.f}; acc[i][j] = z; }
        #pragma unroll
        for (int k0 = 0; k0 < 128; k0 += 32) {
            bf8 bv[3];
            #pragma unroll
            for (int jj = 0; jj < 3; jj++) {
                int n = (3 * w + jj) * 16 + lrow;
                bv[jj] = *(const bf8*)&qkvw[(size_t)n * 128 + k0 + quad * 8];
            }
            #pragma unroll
            for (int i = 0; i < 5; i++) {
                bf8 av = *(const bf8*)&xs[swz8(i * 16 + lrow, k0 + quad * 8)];
                #pragma unroll
                for (int jj = 0; jj < 3; jj++)
                    acc[i][jj] = __builtin_amdgcn_mfma_f32_16x16x32_bf16(
                        bv[jj], av, acc[i][jj], 0, 0, 0);   // C^T fragment
            }
        }
        __syncthreads();          // xs reads done before qo overlay writes
        #pragma unroll
        for (int jj = 0; jj < 3; jj++) {
            int jt = 3 * w + jj;
            int n0 = jt * 16 + quad * 4;         // 4 consecutive N-cols
            float4 b4 = *(const float4*)&qkvb[n0];
            #pragma unroll
            for (int i = 0; i < 5; i++) {
                int m = i * 16 + lrow;           // one M-row per lane
                float v[4];
                v[0] = acc[i][jj][0] + b4.x; v[1] = acc[i][jj][1] + b4.y;
                v[2] = acc[i][jj][2] + b4.z; v[3] = acc[i][jj][3] + b4.w;
                if (jt < 8) {
                    if (m >= 3 && m < 67) {
                        #pragma unroll
                        for (int r = 0; r < 4; r++) v[r] *= 0.17677669529663687f;
                        st4h(&qo[swz8(m - 3, n0)], v);   // f16
                    }
                } else {
                    if (m < 70) st4h(&kv[swzK(m, n0 - 128)], v);   // f16
                }
            }
        }
    }
    __syncthreads();

    // ---- phase 3: attention, packed f16.
    //      thread = (token=tid>>3, head=(tid>>1)&3, half=tid&1)
    {
        int t = tid >> 3, head = (tid >> 1) & 3, half = tid & 1;
        int n = nl0 + t;
        int s = n - 3;
        if (s < 0) s = 0;
        if (s > NPOS - 7) s = NPOS - 7;
        int r0 = s - nl0 + 3;            // kv row of neighbor j=0
        int cb = head * 32 + half * 16;

        __half2 qh[8];
        ldh8(&qo[swz8(t, cb)], qh);
        ldh8(&qo[swz8(t, cb + 8)], qh + 4);

        float logit[7];
        #pragma unroll
        for (int j = 0; j < 7; j++) {
            int row = r0 + j;
            __half2 ka[4], kb[4];
            ldh8(&kv[swzK(row, cb)], ka);
            ldh8(&kv[swzK(row, cb + 8)], kb);
            __half2 a0 = __hmul2(qh[0], ka[0]);
            __half2 a1 = __hmul2(qh[1], ka[1]);
            a0 = __hfma2(qh[2], ka[2], a0);
            a1 = __hfma2(qh[3], ka[3], a1);
            a0 = __hfma2(qh[4], kb[0], a0);
            a1 = __hfma2(qh[5], kb[1], a1);
            a0 = __hfma2(qh[6], kb[2], a0);
            a1 = __hfma2(qh[7], kb[3], a1);
            a0 = __hadd2(a0, a1);
            float p = __low2float(a0) + __high2float(a0);
            p += __shfl_xor(p, 1, 64);   // combine the two 16-chan halves
            logit[j] = p + rpb[head * 13 + (s + j - n + 6)];
        }
        float m = logit[0];
        #pragma unroll
        for (int j = 1; j < 7; j++) m = fmaxf(m, logit[j]);
        float e[7], esum = 0.f;
        #pragma unroll
        for (int j = 0; j < 7; j++) { e[j] = __expf(logit[j] - m); esum += e[j]; }
        float inv = 1.0f / esum;

        __half2 o[8];
        __half2 zz = __float2half2_rn(0.f);
        #pragma unroll
        for (int c = 0; c < 8; c++) o[c] = zz;
        #pragma unroll
        for (int j = 0; j < 7; j++) {
            int row = r0 + j;
            __half2 ej = __float2half2_rn(e[j] * inv);   // inv folded in
            __half2 va[4], vb[4];
            ldh8(&kv[swzK(row, 128 + cb)], va);
            ldh8(&kv[swzK(row, 128 + cb + 8)], vb);
            o[0] = __hfma2(ej, va[0], o[0]);
            o[1] = __hfma2(ej, va[1], o[1]);
            o[2] = __hfma2(ej, va[2], o[2]);
            o[3] = __hfma2(ej, va[3], o[3]);
            o[4] = __hfma2(ej, vb[0], o[4]);
            o[5] = __hfma2(ej, vb[1], o[5]);
            o[6] = __hfma2(ej, vb[2], o[6]);
            o[7] = __hfma2(ej, vb[3], o[7]);
        }
        sth8(&qo[swz8(t, cb)], o);
        sth8(&qo[swz8(t, cb + 8)], o + 4);
    }
    __syncthreads();

    // ---- phase 4: proj (f16 MFMA, transposed C) + x resid (float4) -> ct
    {
        int nb = w * 16 + lrow;              // weight row for B-frag loads
        int n0 = w * 16 + quad * 4;          // 4 consecutive out cols
        f4 acc2[4];
        #pragma unroll
        for (int i = 0; i < 4; i++) { f4 z = {0.f,0.f,0.f,0.f}; acc2[i] = z; }
        #pragma unroll
        for (int k0 = 0; k0 < 128; k0 += 32) {
            h8 bv = *(const h8*)&projw[(size_t)nb * 128 + k0 + quad * 8];
            #pragma unroll
            for (int i = 0; i < 4; i++) {
                h8 av = *(const h8*)&qo[swz8(i * 16 + lrow, k0 + quad * 8)];
                acc2[i] = __builtin_amdgcn_mfma_f32_16x16x32_f16(bv, av, acc2[i], 0, 0, 0);
            }
        }
        float4 b4 = *(const float4*)&projb[n0];
        #pragma unroll
        for (int i = 0; i < 4; i++) {
            int m = i * 16 + lrow;
            float4 xv = *(const float4*)&x[(size_t)(t0 + m) * 128 + n0];
            float v[4];
            v[0] = acc2[i][0] + b4.x + xv.x; v[1] = acc2[i][1] + b4.y + xv.y;
            v[2] = acc2[i][2] + b4.z + xv.z; v[3] = acc2[i][3] + b4.w + xv.w;
            st4(&ct[swz8(m, n0)], v);
        }
    }
    __syncthreads();

    // ---- phase 5: LN2 (16 lanes/row) ct -> ys (overlays qo; qo dead)
    {
        int grp = tid >> 4, l = tid & 15;
        int c0 = l * 8;
        float4 wa = *(const float4*)&n2w[c0], wb = *(const float4*)&n2w[c0 + 4];
        float4 ba = *(const float4*)&n2b[c0], bb = *(const float4*)&n2b[c0 + 4];
        float w8[8] = {wa.x, wa.y, wa.z, wa.w, wb.x, wb.y, wb.z, wb.w};
        float b8[8] = {ba.x, ba.y, ba.z, ba.w, bb.x, bb.y, bb.z, bb.w};
        #pragma unroll
        for (int pass = 0; pass < 2; pass++) {
            int t = pass * 32 + grp;
            float v[8];
            ld8(&ct[swz8(t, c0)], v);
            float s = 0.f, s2 = 0.f;
            #pragma unroll
            for (int e = 0; e < 8; e++) { s += v[e]; s2 += v[e] * v[e]; }
            #pragma unroll
            for (int off = 8; off; off >>= 1) {
                s  += __shfl_xor(s,  off, 64);
                s2 += __shfl_xor(s2, off, 64);
            }
            float mu   = s * (1.0f / 128.0f);
            float rstd = rsqrtf(s2 * (1.0f / 128.0f) - mu * mu + 1e-5f);
            float o[8];
            #pragma unroll
            for (int e = 0; e < 8; e++) o[e] = (v[e] - mu) * rstd * w8[e] + b8[e];
            st8(&ys[swz8(t, c0)], o);
        }
    }
    __syncthreads();

    // ---- phase 6: fc1 + gelu + fc2 by 128-wide K-QUARTERS (transposed C
    //      throughout; h[64][128] coexists with ct) + x2 resid from ct.
    {
        f4 acc2[4];
        #pragma unroll
        for (int i = 0; i < 4; i++) { f4 z = {0.f,0.f,0.f,0.f}; acc2[i] = z; }
        int nb = w * 16 + lrow;              // fc2 weight row (loads)
        int n0 = w * 16 + quad * 4;          // out cols (epilogue)

        for (int qq = 0; qq < 4; qq++) {
            // fc1 quarter: local N=128 (8 tiles, 1/wave), K=128
            f4 acc[4];
            #pragma unroll
            for (int i = 0; i < 4; i++) { f4 z = {0.f,0.f,0.f,0.f}; acc[i] = z; }
            int frow = qq * 128 + w * 16 + lrow;   // fc1 weight row (loads)
            #pragma unroll
            for (int k0 = 0; k0 < 128; k0 += 32) {
                bf8 bv = *(const bf8*)&fc1w[(size_t)frow * 128 + k0 + quad * 8];
                #pragma unroll
                for (int i = 0; i < 4; i++) {
                    bf8 av = *(const bf8*)&ys[swz8(i * 16 + lrow, k0 + quad * 8)];
                    acc[i] = __builtin_amdgcn_mfma_f32_16x16x32_bf16(
                        bv, av, acc[i], 0, 0, 0);
                }
            }
            __syncthreads();   // prior quarter's fc2 done reading h
            {
                int hc0 = w * 16 + quad * 4;       // local hidden col base
                float4 b4 = *(const float4*)&fc1b[qq * 128 + hc0];
                float bb[4] = {b4.x, b4.y, b4.z, b4.w};
                #pragma unroll
                for (int i = 0; i < 4; i++) {
                    int m = i * 16 + lrow;
                    float v[4];
                    #pragma unroll
                    for (int r = 0; r < 4; r++)
                        v[r] = fast_gelu(acc[i][r] + bb[r]);
                    st4(&h[swz8(m, hc0)], v);
                }
            }
            __syncthreads();
            // fc2 partial: K-quarter 128
            #pragma unroll
            for (int k0 = 0; k0 < 128; k0 += 32) {
                bf8 bv = *(const bf8*)&fc2w[(size_t)nb * 512 + qq * 128 + k0 + quad * 8];
                #pragma unroll
                for (int i = 0; i < 4; i++) {
                    bf8 av = *(const bf8*)&h[swz8(i * 16 + lrow, k0 + quad * 8)];
                    acc2[i] = __builtin_amdgcn_mfma_f32_16x16x32_bf16(bv, av, acc2[i], 0, 0, 0);
                }
            }
        }

        float4 b4 = *(const float4*)&fc2b[n0];
        #pragma unroll
        for (int i = 0; i < 4; i++) {
            int m = i * 16 + lrow;
            float rv[4];
            ld4(&ct[swz8(m, n0)], rv);
            float4 o;
            o.x = acc2[i][0] + b4.x + rv[0];
            o.y = acc2[i][1] + b4.y + rv[1];
            o.z = acc2[i][2] + b4.z + rv[2];
            o.w = acc2[i][3] + b4.w + rv[3];
            *(float4*)&out[(size_t)(t0 + m) * 128 + n0] = o;
        }
    }
}

extern "C" void kernel_launch(void* const* d_in, const int* in_sizes, int n_in,
                              void* d_out, int out_size, void* d_ws, size_t ws_size,
                              hipStream_t stream) {
    const float* x      = (const float*)d_in[0];
    const float* n1w    = (const float*)d_in[1];
    const float* n1b    = (const float*)d_in[2];
    const float* qkv_w  = (const float*)d_in[3];
    const float* qkv_b  = (const float*)d_in[4];
    const float* rpb    = (const float*)d_in[5];
    const float* proj_w = (const float*)d_in[6];
    const float* proj_b = (const float*)d_in[7];
    const float* n2w    = (const float*)d_in[8];
    const float* n2b    = (const float*)d_in[9];
    const float* fc1_w  = (const float*)d_in[10];
    const float* fc1_b  = (const float*)d_in[11];
    const float* fc2_w  = (const float*)d_in[12];
    const float* fc2_b  = (const float*)d_in[13];

    ushort_t* params = (ushort_t*)d_ws;
    float*    outf   = (float*)d_out;

    cvt_params<<<(P_TOTAL + 255) / 256, 256, 0, stream>>>(
        qkv_w, qkv_b, proj_w, proj_b, fc1_w, fc1_b, fc2_w, fc2_b, params);

    k_fused<<<MROWS / 64, 512, 53760, stream>>>(
        x, n1w, n1b, params + P_QKV_W, qkv_b, rpb,
        params + P_PROJ_W, proj_b, n2w, n2b,
        params + P_FC1_W, fc1_b, params + P_FC2_W, fc2_b, outf);
}